// Round 3
// baseline (8936.131 us; speedup 1.0000x reference)
//
#include <hip/hip_runtime.h>
#include <hip/hip_bf16.h>
#include <stdint.h>

typedef __bf16 bf16_t;
typedef __bf16 bf16x8 __attribute__((ext_vector_type(8)));
typedef float f32x4 __attribute__((ext_vector_type(4)));

#define T_STEPS 64
#define BATCH   512
#define NTOKC   512
#define NINP    600
#define NHID    600
#define NBLK    6
#define BSZ     100
#define DK      64
#define ATTD    340
#define DC      32
#define KU_N    384     // 64 (k1) + 300 (u) + pad
#define OUT_KP  608     // NHID padded for dec GEMM K

// workspace layout (bytes), all 16B aligned
#define WS_KU     0u                 // 32768*384*4  = 50331648
#define WS_OUTB   50331648u          // 32768*608*2  = 39845888
#define WS_W1     90177536u          // 512*384*4    = 786432
#define WS_B1     90963968u          // 384*4        = 1536
#define WS_WVWX   90965504u          // 600*300*4    = 720000
#define WS_DECWT  91685504u          // 512*608*2    = 622592  (end ~92.3 MB)

// ---------------- prep kernels (tiny fp32 GEMMs) ----------------

__global__ void prep_wvwx(const float* __restrict__ Wv, const float* __restrict__ Wx,
                          float* __restrict__ WvWx) {
    int idx = blockIdx.x * 256 + threadIdx.x;
    if (idx >= NINP * 300) return;
    int i = idx / 300, c = idx % 300;
    float acc = 0.f;
    for (int a = 0; a < ATTD; a++) acc += Wv[i * ATTD + a] * Wx[a * 300 + c];
    WvWx[i * 300 + c] = acc;
}

__global__ void prep_w1(const float* __restrict__ encW, const float* __restrict__ Wk,
                        const float* __restrict__ WvWx, float* __restrict__ W1) {
    int idx = blockIdx.x * 256 + threadIdx.x;
    if (idx >= NTOKC * KU_N) return;
    int i = idx / KU_N, c = idx % KU_N;
    float acc = 0.f;
    if (c < DK) {
        for (int k = 0; k < NINP; k++) acc += encW[i * NINP + k] * Wk[k * DK + c];
    } else if (c < DK + 300) {
        int cc = c - DK;
        for (int k = 0; k < NINP; k++) acc += encW[i * NINP + k] * WvWx[k * 300 + cc];
    }
    W1[idx] = acc;
}

__global__ void prep_b1(const float* __restrict__ encB, const float* __restrict__ Wk,
                        const float* __restrict__ WvWx, float* __restrict__ b1) {
    int c = blockIdx.x * 256 + threadIdx.x;
    if (c >= KU_N) return;
    float acc = 0.f;
    if (c < DK) {
        for (int k = 0; k < NINP; k++) acc += encB[k] * Wk[k * DK + c];
    } else if (c < DK + 300) {
        int cc = c - DK;
        for (int k = 0; k < NINP; k++) acc += encB[k] * WvWx[k * 300 + cc];
    }
    b1[c] = acc;
}

__global__ void prep_decwt(const float* __restrict__ decW, bf16_t* __restrict__ decWT) {
    int idx = blockIdx.x * 256 + threadIdx.x;
    if (idx >= NTOKC * OUT_KP) return;
    int n = idx / OUT_KP, k = idx % OUT_KP;
    decWT[idx] = (k < NHID) ? (bf16_t)decW[k * NTOKC + n] : (bf16_t)0.f;
}

// ---------------- KU = input @ W1 + b1 (fp32; precision-critical) ----------------

__global__ __launch_bounds__(256) void ku_gemm(const float* __restrict__ A,
                                               const float* __restrict__ W1,
                                               const float* __restrict__ b1,
                                               float* __restrict__ KU) {
    __shared__ float As[16][128];
    __shared__ float Bs[16][64];
    const int tid = threadIdx.x;
    const int m0 = blockIdx.x * 128, n0 = blockIdx.y * 64;
    const int ty = tid >> 4, tx = tid & 15;
    const int bk = tid >> 6, bn = tid & 63;
    float acc[8][4] = {};
    for (int k0 = 0; k0 < NTOKC; k0 += 16) {
#pragma unroll
        for (int ii = 0; ii < 2; ii++) {
            int t2 = tid + ii * 256;
            int ar = t2 >> 2, ac4 = (t2 & 3) << 2;
            float4 raw = *(const float4*)(A + (size_t)(m0 + ar) * NTOKC + k0 + ac4);
            As[ac4 + 0][ar] = raw.x;
            As[ac4 + 1][ar] = raw.y;
            As[ac4 + 2][ar] = raw.z;
            As[ac4 + 3][ar] = raw.w;
        }
#pragma unroll
        for (int i = 0; i < 4; i++) {
            int kk = bk + (i << 2);
            Bs[kk][bn] = W1[(size_t)(k0 + kk) * KU_N + n0 + bn];
        }
        __syncthreads();
#pragma unroll
        for (int kk = 0; kk < 16; kk++) {
            float4 a0 = *(const float4*)&As[kk][ty * 8];
            float4 a1 = *(const float4*)&As[kk][ty * 8 + 4];
            float4 bv = *(const float4*)&Bs[kk][tx * 4];
            float av[8] = {a0.x, a0.y, a0.z, a0.w, a1.x, a1.y, a1.z, a1.w};
            float bw[4] = {bv.x, bv.y, bv.z, bv.w};
#pragma unroll
            for (int r = 0; r < 8; r++)
#pragma unroll
                for (int c = 0; c < 4; c++) acc[r][c] += av[r] * bw[c];
        }
        __syncthreads();
    }
#pragma unroll
    for (int r = 0; r < 8; r++) {
        int m = m0 + ty * 8 + r;
#pragma unroll
        for (int c = 0; c < 4; c++) {
            int n = n0 + tx * 4 + c;
            KU[(size_t)m * KU_N + n] = acc[r][c] + b1[n];
        }
    }
}

// ---------------- persistent scan v2: 1 batch/WG, 512 WGs x 384 thr ----------------
// threads 0..191  : hold 2 cols of W_a=[Wq|Wh] in VGPRs (cols tid, tid+192)
// threads 192..355: hold 1 col of W_b=[Wq2|Wk2|Wv2]      (col tid-192)

__global__ __launch_bounds__(384) void scan_kernel(
    const float* __restrict__ hidden, const float* __restrict__ masks,
    const float* __restrict__ Wq, const float* __restrict__ Wh,
    const float* __restrict__ grub, const float* __restrict__ Wq2,
    const float* __restrict__ Wk2, const float* __restrict__ Wv2,
    const float* __restrict__ KU, bf16_t* __restrict__ outb,
    float* __restrict__ hT_out, float* __restrict__ bm_out) {
    __shared__ float hsh[600];        // h_stored (unmasked)
    __shared__ float ush[300];        // u row
    __shared__ float grubs[304];
    __shared__ float hgs[1800];       // hg; cols [0,100) become hn after GRU
    __shared__ float qkvs[NBLK * 164];// q2|k2|v2 per block row
    __shared__ float p1sh[8];
    __shared__ float bmvs[8];
    __shared__ float p2l[40];
    __shared__ float p2s6[40];

    const int tid = threadIdx.x;
    const int b = blockIdx.x;

    // ---- weight preload into registers ----
    float w[200];
    if (tid < 192) {
        const float* p0; int st0;
        if (tid < 64) { p0 = Wq + tid; st0 = 64; } else { p0 = Wh + (tid - 64); st0 = 300; }
#pragma unroll
        for (int k = 0; k < 100; k++) w[k] = p0[k * st0];
        const int j1 = tid + 192;               // always >= 192: Wh col j1-64 if < 364
        const float* p1 = Wh + (j1 - 64);
        const bool ok = (j1 < 364);
#pragma unroll
        for (int k = 0; k < 100; k++) w[100 + k] = ok ? p1[k * 300] : 0.f;
    } else if (tid < 356) {
        const int j = tid - 192;
        const float* p0; int st0;
        if (j < 32) { p0 = Wq2 + j; st0 = 32; }
        else if (j < 64) { p0 = Wk2 + (j - 32); st0 = 32; }
        else { p0 = Wv2 + (j - 64); st0 = 100; }
#pragma unroll
        for (int k = 0; k < 100; k++) w[k] = p0[k * st0];
    }

    // ---- init LDS: h, grub ----
    if (tid < 300) grubs[tid] = grub[tid];
    {
        int i0 = tid;
        hsh[i0] = (i0 < 600) ? hidden[(size_t)b * NHID + i0] : 0.f;  // tid<384 always <600? yes 384<600
        int i1 = tid + 384;
        if (i1 < 600) hsh[i1] = hidden[(size_t)b * NHID + i1];
    }
    __syncthreads();

    for (int t = 0; t < T_STEPS; t++) {
        const float mval = masks[t * BATCH + b];
        const size_t rowoff = (size_t)(t * BATCH + b) * KU_N;
        float k1r = 0.f, ur = 0.f;
        if (tid < 64) k1r = KU[rowoff + tid];
        else if (tid < 364) ur = KU[rowoff + tid];

        // ---- P1: [q|hg] = h @ [Wq|Wh] on threads 0..191 (2 cols each) ----
        if (tid < 192) {
            float a0[6] = {0.f, 0.f, 0.f, 0.f, 0.f, 0.f};
            float a1[6] = {0.f, 0.f, 0.f, 0.f, 0.f, 0.f};
#pragma unroll
            for (int kc = 0; kc < 25; kc++) {
                const float w00 = w[4 * kc], w01 = w[4 * kc + 1], w02 = w[4 * kc + 2], w03 = w[4 * kc + 3];
                const float w10 = w[100 + 4 * kc], w11 = w[100 + 4 * kc + 1],
                            w12 = w[100 + 4 * kc + 2], w13 = w[100 + 4 * kc + 3];
#pragma unroll
                for (int n = 0; n < 6; n++) {
                    float4 hv = *(const float4*)&hsh[n * 100 + 4 * kc];
                    a0[n] += hv.x * w00; a0[n] += hv.y * w01; a0[n] += hv.z * w02; a0[n] += hv.w * w03;
                    a1[n] += hv.x * w10; a1[n] += hv.y * w11; a1[n] += hv.z * w12; a1[n] += hv.w * w13;
                }
            }
            if (tid >= 64) {
#pragma unroll
                for (int n = 0; n < 6; n++) hgs[n * 300 + (tid - 64)] = mval * a0[n];
            } else {
                // wave 0: scores via 64-lane butterfly; p1/top-k in registers
                float pv[6];
#pragma unroll
                for (int n = 0; n < 6; n++) {
                    float v = a0[n] * k1r;
#pragma unroll
                    for (int off = 32; off > 0; off >>= 1) v += __shfl_xor(v, off, 64);
                    float s = v * 0.125f * mval;
                    pv[n] = 1.f / (1.f + __expf(-s) * 0.f + expf(-s));  // keep precise expf
                }
                if (tid < 6) {
                    float pn = pv[tid];
                    int cnt = 0;
#pragma unroll
                    for (int j2 = 0; j2 < 6; j2++)
                        cnt += (pv[j2] > pn || (pv[j2] == pn && j2 < tid)) ? 1 : 0;
                    float bm = (cnt < 4) ? 1.f : 0.f;
                    p1sh[tid] = pv[tid];
                    bmvs[tid] = bm;
                    bm_out[(size_t)(t * BATCH + b) * NBLK + tid] = bm;
                }
            }
            if (tid < 172) {
#pragma unroll
                for (int n = 0; n < 6; n++) hgs[n * 300 + (tid + 128)] = mval * a1[n];
            }
        }
        if (tid >= 64 && tid < 364) ush[tid - 64] = ur;
        __syncthreads();   // B1

        // ---- P2: GRU -> hn (into hgs cols [0,100)) ----
        if (tid < 300) {
            const int e = 2 * tid, n = e / 100, c = e % 100;
            const float p1 = p1sh[n];
            float2 u0 = *(const float2*)&ush[c];
            float2 u1 = *(const float2*)&ush[100 + c];
            float2 u2 = *(const float2*)&ush[200 + c];
            float2 g0 = *(const float2*)&grubs[c];
            float2 g1 = *(const float2*)&grubs[100 + c];
            float2 g2 = *(const float2*)&grubs[200 + c];
            float2 hr = *(const float2*)&hgs[n * 300 + c];
            float2 hz = *(const float2*)&hgs[n * 300 + 100 + c];
            float2 hnn = *(const float2*)&hgs[n * 300 + 200 + c];
            float2 hb = *(const float2*)&hsh[n * 100 + c];
            hb.x *= mval; hb.y *= mval;
            float rx = 1.f / (1.f + expf(-(p1 * u0.x + g0.x + hr.x)));
            float ry = 1.f / (1.f + expf(-(p1 * u0.y + g0.y + hr.y)));
            float zx = 1.f / (1.f + expf(-(p1 * u1.x + g1.x + hz.x)));
            float zy = 1.f / (1.f + expf(-(p1 * u1.y + g1.y + hz.y)));
            float nx = tanhf(p1 * u2.x + g2.x + rx * hnn.x);
            float ny = tanhf(p1 * u2.y + g2.y + ry * hnn.y);
            float2 hn2;
            hn2.x = (1.f - zx) * nx + zx * hb.x;
            hn2.y = (1.f - zy) * ny + zy * hb.y;
            *(float2*)&hgs[n * 300 + c] = hn2;
        }
        __syncthreads();   // B2

        // ---- P3: [q2|k2|v2] = hn @ W_b on threads 192..355 ----
        if (tid >= 192 && tid < 356) {
            const int j = tid - 192;
            float a[6] = {0.f, 0.f, 0.f, 0.f, 0.f, 0.f};
#pragma unroll
            for (int kc = 0; kc < 25; kc++) {
                const float w0 = w[4 * kc], w1 = w[4 * kc + 1], w2 = w[4 * kc + 2], w3 = w[4 * kc + 3];
#pragma unroll
                for (int n = 0; n < 6; n++) {
                    float4 hv = *(const float4*)&hgs[n * 300 + 4 * kc];
                    a[n] += hv.x * w0; a[n] += hv.y * w1; a[n] += hv.z * w2; a[n] += hv.w * w3;
                }
            }
#pragma unroll
            for (int n = 0; n < 6; n++) qkvs[n * 164 + j] = a[n];
        }
        __syncthreads();   // B3

        // ---- P4: p2 = softmax(q2 k2^T / sqrt(32))  (wave 0 only) ----
        if (tid < 36) {
            const int n = tid / 6, mcol = tid % 6;
            float e = 0.f;
#pragma unroll
            for (int d = 0; d < 32; d++) e += qkvs[n * 164 + d] * qkvs[mcol * 164 + 32 + d];
            p2l[tid] = e * 0.17677669529663687f;
        }
        // same wave: LDS program order makes p2l visible
        if (tid < 36) {
            const int n = tid / 6;
            float mx = p2l[n * 6];
#pragma unroll
            for (int m2 = 1; m2 < 6; m2++) mx = fmaxf(mx, p2l[n * 6 + m2]);
            float sum = 0.f;
#pragma unroll
            for (int m2 = 0; m2 < 6; m2++) sum += expf(p2l[n * 6 + m2] - mx);
            p2s6[tid] = expf(p2l[tid] - mx) / sum;
        }
        __syncthreads();   // B4

        // ---- P5: hc = hn + p2@v2; blend; write h/outb/hT ----
        if (tid < 300) {
            const int e = 2 * tid, n = e / 100, c = e % 100;
            float2 acc = *(const float2*)&hgs[n * 300 + c];   // hn
#pragma unroll
            for (int m2 = 0; m2 < 6; m2++) {
                const float p = p2s6[n * 6 + m2];
                float2 v = *(const float2*)&qkvs[m2 * 164 + 64 + c];
                acc.x += p * v.x; acc.y += p * v.y;
            }
            float2 hb = *(const float2*)&hsh[n * 100 + c];
            hb.x *= mval; hb.y *= mval;
            const float bm = bmvs[n];
            float nx = (bm != 0.f) ? acc.x : hb.x;
            float ny = (bm != 0.f) ? acc.y : hb.y;
            hsh[n * 100 + c] = nx;
            hsh[n * 100 + c + 1] = ny;
            const size_t ro = (size_t)(t * BATCH + b) * OUT_KP + n * 100 + c;
            union { bf16_t h2[2]; uint32_t u32; } pk;
            pk.h2[0] = (bf16_t)nx; pk.h2[1] = (bf16_t)ny;
            *(uint32_t*)&outb[ro] = pk.u32;
            if (t == T_STEPS - 1) {
                hT_out[(size_t)b * NHID + n * 100 + c] = nx;
                hT_out[(size_t)b * NHID + n * 100 + c + 1] = ny;
            }
        } else if (tid < 304) {
            const int c = 2 * (tid - 300);
            const size_t ro = (size_t)(t * BATCH + b) * OUT_KP + NHID + c;
            union { bf16_t h2[2]; uint32_t u32; } pk;
            pk.h2[0] = (bf16_t)0.f; pk.h2[1] = (bf16_t)0.f;
            *(uint32_t*)&outb[ro] = pk.u32;
        }
        __syncthreads();   // B5
    }
}

// ---------------- dec = outb @ decWT^T + dec_b (bf16 MFMA 16x16x32) ----------------

__global__ __launch_bounds__(256) void dec_gemm(const bf16_t* __restrict__ Ag,
                                                const bf16_t* __restrict__ Bg,
                                                const float* __restrict__ bias,
                                                float* __restrict__ C) {
    __shared__ bf16_t As[128][32];
    __shared__ bf16_t Bs[64][32];
    const int tid = threadIdx.x;
    const int wave = tid >> 6, lane = tid & 63;
    const int m0 = blockIdx.x * 128, n0 = blockIdx.y * 64;
    f32x4 acc[2][4] = {};
    for (int k0 = 0; k0 < OUT_KP; k0 += 32) {
#pragma unroll
        for (int ii = 0; ii < 2; ii++) {
            int el = (tid + ii * 256) * 8;
            int row = el >> 5, col = el & 31;
            *(float4*)&As[row][col] = *(const float4*)(Ag + (size_t)(m0 + row) * OUT_KP + k0 + col);
        }
        {
            int el = tid * 8;
            int row = el >> 5, col = el & 31;
            *(float4*)&Bs[row][col] = *(const float4*)(Bg + (size_t)(n0 + row) * OUT_KP + k0 + col);
        }
        __syncthreads();
        const int fm = lane & 15, fq = (lane >> 4) * 8;
        bf16x8 a[2], bb[4];
        a[0] = *(const bf16x8*)&As[wave * 32 + fm][fq];
        a[1] = *(const bf16x8*)&As[wave * 32 + 16 + fm][fq];
#pragma unroll
        for (int nt = 0; nt < 4; nt++) bb[nt] = *(const bf16x8*)&Bs[nt * 16 + fm][fq];
#pragma unroll
        for (int mt = 0; mt < 2; mt++)
#pragma unroll
            for (int nt = 0; nt < 4; nt++)
                acc[mt][nt] = __builtin_amdgcn_mfma_f32_16x16x32_bf16(a[mt], bb[nt], acc[mt][nt], 0, 0, 0);
        __syncthreads();
    }
    const int fm = lane & 15, fr = (lane >> 4) * 4;
#pragma unroll
    for (int mt = 0; mt < 2; mt++)
#pragma unroll
        for (int nt = 0; nt < 4; nt++) {
            int n = n0 + nt * 16 + fm;
            float bia = bias[n];
#pragma unroll
            for (int r = 0; r < 4; r++) {
                int m = m0 + wave * 32 + mt * 16 + fr + r;
                C[(size_t)m * NTOKC + n] = acc[mt][nt][r] + bia;
            }
        }
}

// ---------------- launch ----------------

extern "C" void kernel_launch(void* const* d_in, const int* in_sizes, int n_in,
                              void* d_out, int out_size, void* d_ws, size_t ws_size,
                              hipStream_t stream) {
    const float* input  = (const float*)d_in[0];
    const float* hidden = (const float*)d_in[1];
    const float* masks  = (const float*)d_in[2];
    const float* encW   = (const float*)d_in[3];
    const float* encB   = (const float*)d_in[4];
    const float* Wq     = (const float*)d_in[5];
    const float* Wk     = (const float*)d_in[6];
    const float* Wv     = (const float*)d_in[7];
    const float* Wx     = (const float*)d_in[8];
    const float* Wh     = (const float*)d_in[9];
    const float* grub   = (const float*)d_in[10];
    const float* Wq2    = (const float*)d_in[11];
    const float* Wk2    = (const float*)d_in[12];
    const float* Wv2    = (const float*)d_in[13];
    const float* decW   = (const float*)d_in[14];
    const float* decB   = (const float*)d_in[15];

    char* ws = (char*)d_ws;
    float*  KU    = (float*)(ws + WS_KU);
    bf16_t* outb  = (bf16_t*)(ws + WS_OUTB);
    float*  W1    = (float*)(ws + WS_W1);
    float*  b1    = (float*)(ws + WS_B1);
    float*  WvWx  = (float*)(ws + WS_WVWX);
    bf16_t* decWT = (bf16_t*)(ws + WS_DECWT);

    float* out_dec = (float*)d_out;
    float* out_hT  = out_dec + 16777216;   // T*B*NTOK
    float* out_bm  = out_dec + 17084416;   // + B*NHID

    prep_wvwx<<<(NINP * 300 + 255) / 256, 256, 0, stream>>>(Wv, Wx, WvWx);
    prep_w1<<<(NTOKC * KU_N + 255) / 256, 256, 0, stream>>>(encW, Wk, WvWx, W1);
    prep_b1<<<2, 256, 0, stream>>>(encB, Wk, WvWx, b1);
    prep_decwt<<<(NTOKC * OUT_KP + 255) / 256, 256, 0, stream>>>(decW, decWT);
    ku_gemm<<<dim3(256, 6), 256, 0, stream>>>(input, W1, b1, KU);
    scan_kernel<<<512, 384, 0, stream>>>(hidden, masks, Wq, Wh, grub, Wq2, Wk2, Wv2,
                                         KU, outb, out_hT, out_bm);
    dec_gemm<<<dim3(256, 8), 256, 0, stream>>>(outb, decWT, decB, out_dec);
}

// Round 4
// 1890.260 us; speedup vs baseline: 4.7275x; 4.7275x over previous
//
#include <hip/hip_runtime.h>
#include <hip/hip_bf16.h>
#include <stdint.h>

typedef __bf16 bf16_t;
typedef __bf16 bf16x8 __attribute__((ext_vector_type(8)));
typedef float f32x4 __attribute__((ext_vector_type(4)));

#define T_STEPS 64
#define BATCH   512
#define NTOKC   512
#define NINP    600
#define NHID    600
#define NBLK    6
#define BSZ     100
#define DK      64
#define ATTD    340
#define DC      32
#define KU_N    384     // 64 (k1) + 300 (u) + pad
#define OUT_KP  608     // NHID padded for dec GEMM K

// workspace layout (bytes), all 16B aligned
#define WS_KU     0u                 // 32768*384*4  = 50331648
#define WS_OUTB   50331648u          // 32768*608*2  = 39845888
#define WS_W1     90177536u          // 512*384*4    = 786432
#define WS_B1     90963968u          // 384*4        = 1536
#define WS_WVWX   90965504u          // 600*300*4    = 720000
#define WS_DECWT  91685504u          // 512*608*2    = 622592  (end ~92.3 MB)

// ---------------- prep kernels (tiny fp32 GEMMs) ----------------

__global__ void prep_wvwx(const float* __restrict__ Wv, const float* __restrict__ Wx,
                          float* __restrict__ WvWx) {
    int idx = blockIdx.x * 256 + threadIdx.x;
    if (idx >= NINP * 300) return;
    int i = idx / 300, c = idx % 300;
    float acc = 0.f;
    for (int a = 0; a < ATTD; a++) acc += Wv[i * ATTD + a] * Wx[a * 300 + c];
    WvWx[i * 300 + c] = acc;
}

__global__ void prep_w1(const float* __restrict__ encW, const float* __restrict__ Wk,
                        const float* __restrict__ WvWx, float* __restrict__ W1) {
    int idx = blockIdx.x * 256 + threadIdx.x;
    if (idx >= NTOKC * KU_N) return;
    int i = idx / KU_N, c = idx % KU_N;
    float acc = 0.f;
    if (c < DK) {
        for (int k = 0; k < NINP; k++) acc += encW[i * NINP + k] * Wk[k * DK + c];
    } else if (c < DK + 300) {
        int cc = c - DK;
        for (int k = 0; k < NINP; k++) acc += encW[i * NINP + k] * WvWx[k * 300 + cc];
    }
    W1[idx] = acc;
}

__global__ void prep_b1(const float* __restrict__ encB, const float* __restrict__ Wk,
                        const float* __restrict__ WvWx, float* __restrict__ b1) {
    int c = blockIdx.x * 256 + threadIdx.x;
    if (c >= KU_N) return;
    float acc = 0.f;
    if (c < DK) {
        for (int k = 0; k < NINP; k++) acc += encB[k] * Wk[k * DK + c];
    } else if (c < DK + 300) {
        int cc = c - DK;
        for (int k = 0; k < NINP; k++) acc += encB[k] * WvWx[k * 300 + cc];
    }
    b1[c] = acc;
}

__global__ void prep_decwt(const float* __restrict__ decW, bf16_t* __restrict__ decWT) {
    int idx = blockIdx.x * 256 + threadIdx.x;
    if (idx >= NTOKC * OUT_KP) return;
    int n = idx / OUT_KP, k = idx % OUT_KP;
    decWT[idx] = (k < NHID) ? (bf16_t)decW[k * NTOKC + n] : (bf16_t)0.f;
}

// ---------------- KU = input @ W1 + b1 (fp32; precision-critical) ----------------

__global__ __launch_bounds__(256) void ku_gemm(const float* __restrict__ A,
                                               const float* __restrict__ W1,
                                               const float* __restrict__ b1,
                                               float* __restrict__ KU) {
    __shared__ float As[16][128];
    __shared__ float Bs[16][64];
    const int tid = threadIdx.x;
    const int m0 = blockIdx.x * 128, n0 = blockIdx.y * 64;
    const int ty = tid >> 4, tx = tid & 15;
    const int bk = tid >> 6, bn = tid & 63;
    float acc[8][4] = {};
    for (int k0 = 0; k0 < NTOKC; k0 += 16) {
#pragma unroll
        for (int ii = 0; ii < 2; ii++) {
            int t2 = tid + ii * 256;
            int ar = t2 >> 2, ac4 = (t2 & 3) << 2;
            float4 raw = *(const float4*)(A + (size_t)(m0 + ar) * NTOKC + k0 + ac4);
            As[ac4 + 0][ar] = raw.x;
            As[ac4 + 1][ar] = raw.y;
            As[ac4 + 2][ar] = raw.z;
            As[ac4 + 3][ar] = raw.w;
        }
#pragma unroll
        for (int i = 0; i < 4; i++) {
            int kk = bk + (i << 2);
            Bs[kk][bn] = W1[(size_t)(k0 + kk) * KU_N + n0 + bn];
        }
        __syncthreads();
#pragma unroll
        for (int kk = 0; kk < 16; kk++) {
            float4 a0 = *(const float4*)&As[kk][ty * 8];
            float4 a1 = *(const float4*)&As[kk][ty * 8 + 4];
            float4 bv = *(const float4*)&Bs[kk][tx * 4];
            float av[8] = {a0.x, a0.y, a0.z, a0.w, a1.x, a1.y, a1.z, a1.w};
            float bw[4] = {bv.x, bv.y, bv.z, bv.w};
#pragma unroll
            for (int r = 0; r < 8; r++)
#pragma unroll
                for (int c = 0; c < 4; c++) acc[r][c] += av[r] * bw[c];
        }
        __syncthreads();
    }
#pragma unroll
    for (int r = 0; r < 8; r++) {
        int m = m0 + ty * 8 + r;
#pragma unroll
        for (int c = 0; c < 4; c++) {
            int n = n0 + tx * 4 + c;
            KU[(size_t)m * KU_N + n] = acc[r][c] + b1[n];
        }
    }
}

// ---------------- persistent scan v3: 2 batches/WG, 576 thr, register weights ----------------
// thread  0..63  : Wq col tid           (100 regs)  -> q path (wave 0 butterfly scores)
// thread 64..363 : Wh col tid-64        (100 regs)  -> hg
// thread 364..527: [Wq2|Wk2|Wv2] col tid-364 (100 regs) -> q2|k2|v2
// VGPR budget: w[100]+12 acc+temps ~150; __launch_bounds__(576,3) caps at ~170 (no spill).

__global__ __launch_bounds__(576, 3) void scan_kernel(
    const float* __restrict__ hidden, const float* __restrict__ masks,
    const float* __restrict__ Wq, const float* __restrict__ Wh,
    const float* __restrict__ grub, const float* __restrict__ Wq2,
    const float* __restrict__ Wk2, const float* __restrict__ Wv2,
    const float* __restrict__ KU, bf16_t* __restrict__ outb,
    float* __restrict__ hT_out, float* __restrict__ bm_out) {
    __shared__ float hsh[2][600];    // h_stored (unmasked)
    __shared__ float ush[2][300];    // u rows
    __shared__ float grubs[300];
    __shared__ float hgs[2][1800];   // hg; cols [0,100) of each n-block become hn after GRU
    __shared__ float qkvs[2][NBLK * 164];
    __shared__ float p1sh[2][8];
    __shared__ float bmvs[2][8];
    __shared__ float p2l[2][36];
    __shared__ float p2s6[2][40];

    const int tid = threadIdx.x;
    const int b0 = blockIdx.x * 2;

    // ---- weight preload into registers (one 100-col per thread) ----
    float w[100];
    if (tid < 64) {
#pragma unroll
        for (int k = 0; k < 100; k++) w[k] = Wq[k * DK + tid];
    } else if (tid < 364) {
        const int j = tid - 64;
#pragma unroll
        for (int k = 0; k < 100; k++) w[k] = Wh[k * 300 + j];
    } else if (tid < 528) {
        const int j = tid - 364;
        const float* p0; int st0;
        if (j < 32) { p0 = Wq2 + j; st0 = 32; }
        else if (j < 64) { p0 = Wk2 + (j - 32); st0 = 32; }
        else { p0 = Wv2 + (j - 64); st0 = 100; }
#pragma unroll
        for (int k = 0; k < 100; k++) w[k] = p0[k * st0];
    }

    // ---- init LDS: h (2 batches), grub ----
    if (tid < 300) grubs[tid] = grub[tid];
    for (int idx = tid; idx < 1200; idx += 576) {
        int b2 = idx / 600, e = idx % 600;
        hsh[b2][e] = hidden[(size_t)(b0 + b2) * NHID + e];
    }
    __syncthreads();

    for (int t = 0; t < T_STEPS; t++) {
        const float mv0 = masks[t * BATCH + b0];
        const float mv1 = masks[t * BATCH + b0 + 1];
        const size_t row0 = (size_t)(t * BATCH + b0) * KU_N;
        const size_t row1 = row0 + KU_N;
        float k10 = 0.f, k11 = 0.f;
        if (tid < 64) {
            k10 = KU[row0 + tid];
            k11 = KU[row1 + tid];
        } else if (tid < 364) {
            ush[0][tid - 64] = KU[row0 + tid];
            ush[1][tid - 64] = KU[row1 + tid];
        }

        // ---- P1: [q|hg] = h @ [Wq|Wh] (threads 0..363); scores in wave 0 ----
        if (tid < 364) {
            float a0[2][6] = {};
#pragma unroll
            for (int kc = 0; kc < 25; kc++) {
                const float w0 = w[4 * kc], w1 = w[4 * kc + 1],
                            w2 = w[4 * kc + 2], w3 = w[4 * kc + 3];
#pragma unroll
                for (int b2 = 0; b2 < 2; b2++)
#pragma unroll
                    for (int n = 0; n < 6; n++) {
                        float4 hv = *(const float4*)&hsh[b2][n * 100 + 4 * kc];
                        a0[b2][n] += hv.x * w0; a0[b2][n] += hv.y * w1;
                        a0[b2][n] += hv.z * w2; a0[b2][n] += hv.w * w3;
                    }
            }
            if (tid >= 64) {
                const int c = tid - 64;
#pragma unroll
                for (int n = 0; n < 6; n++) {
                    hgs[0][n * 300 + c] = mv0 * a0[0][n];
                    hgs[1][n * 300 + c] = mv1 * a0[1][n];
                }
            } else {
                // wave 0: scores via 64-lane butterfly; p1 + top-k all-lane redundant
                float s[2][6], p[2][6], bmf[2][6];
#pragma unroll
                for (int b2 = 0; b2 < 2; b2++)
#pragma unroll
                    for (int n = 0; n < 6; n++) {
                        float v = a0[b2][n] * (b2 ? k11 : k10);
#pragma unroll
                        for (int off = 32; off > 0; off >>= 1) v += __shfl_xor(v, off, 64);
                        s[b2][n] = v * 0.125f * (b2 ? mv1 : mv0);
                    }
#pragma unroll
                for (int b2 = 0; b2 < 2; b2++)
#pragma unroll
                    for (int n = 0; n < 6; n++) {
                        float sv = s[b2][n];
                        float mx = fmaxf(sv, 0.f);
                        float e0 = expf(0.f - mx), e1 = expf(sv - mx);
                        p[b2][n] = e1 / (e0 + e1);
                    }
#pragma unroll
                for (int b2 = 0; b2 < 2; b2++)
#pragma unroll
                    for (int n = 0; n < 6; n++) {
                        int cnt = 0;
#pragma unroll
                        for (int j2 = 0; j2 < 6; j2++)
                            cnt += (p[b2][j2] > p[b2][n] || (p[b2][j2] == p[b2][n] && j2 < n)) ? 1 : 0;
                        bmf[b2][n] = (cnt < 4) ? 1.f : 0.f;
                    }
                if (tid == 0) {
#pragma unroll
                    for (int b2 = 0; b2 < 2; b2++)
#pragma unroll
                        for (int n = 0; n < 6; n++) {
                            p1sh[b2][n] = p[b2][n];
                            bmvs[b2][n] = bmf[b2][n];
                            bm_out[(size_t)(t * BATCH + b0 + b2) * NBLK + n] = bmf[b2][n];
                        }
                }
            }
        }
        __syncthreads();   // B1: hgs, ush, p1sh, bmvs ready

        // ---- P2: GRU -> hn (into hgs cols [0,100) of each n-block) ----
        for (int idx = tid; idx < 1200; idx += 576) {
            const int b2 = idx / 600, e = idx % 600, n = e / 100, c = e % 100;
            const float mval = b2 ? mv1 : mv0;
            const float p1 = p1sh[b2][n];
            float xr = p1 * ush[b2][c] + grubs[c];
            float xz = p1 * ush[b2][100 + c] + grubs[100 + c];
            float xn = p1 * ush[b2][200 + c] + grubs[200 + c];
            float hr = hgs[b2][n * 300 + c];
            float hz = hgs[b2][n * 300 + 100 + c];
            float hq = hgs[b2][n * 300 + 200 + c];
            float r_ = 1.f / (1.f + expf(-(xr + hr)));
            float z_ = 1.f / (1.f + expf(-(xz + hz)));
            float nn = tanhf(xn + r_ * hq);
            float hold = hsh[b2][e] * mval;
            hgs[b2][n * 300 + c] = (1.f - z_) * nn + z_ * hold;
        }
        __syncthreads();   // B2: hn ready

        // ---- P3: [q2|k2|v2] = hn @ W_b (threads 364..527) ----
        if (tid >= 364 && tid < 528) {
            const int j = tid - 364;
            float a[2][6] = {};
#pragma unroll
            for (int kc = 0; kc < 25; kc++) {
                const float w0 = w[4 * kc], w1 = w[4 * kc + 1],
                            w2 = w[4 * kc + 2], w3 = w[4 * kc + 3];
#pragma unroll
                for (int b2 = 0; b2 < 2; b2++)
#pragma unroll
                    for (int n = 0; n < 6; n++) {
                        float4 hv = *(const float4*)&hgs[b2][n * 300 + 4 * kc];
                        a[b2][n] += hv.x * w0; a[b2][n] += hv.y * w1;
                        a[b2][n] += hv.z * w2; a[b2][n] += hv.w * w3;
                    }
            }
#pragma unroll
            for (int b2 = 0; b2 < 2; b2++)
#pragma unroll
                for (int n = 0; n < 6; n++) qkvs[b2][n * 164 + j] = a[b2][n];
        }
        __syncthreads();   // B3: qkv ready

        // ---- P4: p2 = softmax(q2 k2^T * sc2); b0 on wave 0 lanes 0..35, b1 on wave 1 ----
        {
            const int wv = tid >> 6, ln = tid & 63;
            if (wv < 2 && ln < 36) {
                const int b2 = wv, n = ln / 6, mcol = ln % 6;
                float e = 0.f;
#pragma unroll
                for (int d = 0; d < 32; d++)
                    e += qkvs[b2][n * 164 + d] * qkvs[b2][mcol * 164 + 32 + d];
                p2l[b2][ln] = e * 0.17677669529663687f;
                // same-wave: single ds_write above is wave-wide; reads below see all lanes
                float mx = p2l[b2][n * 6];
#pragma unroll
                for (int m2 = 1; m2 < 6; m2++) mx = fmaxf(mx, p2l[b2][n * 6 + m2]);
                float sum = 0.f;
#pragma unroll
                for (int m2 = 0; m2 < 6; m2++) sum += expf(p2l[b2][n * 6 + m2] - mx);
                p2s6[b2][ln] = expf(p2l[b2][ln] - mx) / sum;
            }
        }
        __syncthreads();   // B4: p2 ready

        // ---- P5: hc = hn + p2@v2; blend by bmask; write h/outb/hT ----
        for (int idx = tid; idx < 1200; idx += 576) {
            const int b2 = idx / 600, e = idx % 600, n = e / 100, c = e % 100;
            const float mval = b2 ? mv1 : mv0;
            float acc = hgs[b2][n * 300 + c];
#pragma unroll
            for (int m2 = 0; m2 < 6; m2++)
                acc += p2s6[b2][n * 6 + m2] * qkvs[b2][m2 * 164 + 64 + c];
            float hold = hsh[b2][e] * mval;
            float hnew = (bmvs[b2][n] != 0.f) ? acc : hold;
            hsh[b2][e] = hnew;
            outb[(size_t)(t * BATCH + b0 + b2) * OUT_KP + e] = (bf16_t)hnew;
            if (t == T_STEPS - 1) hT_out[(size_t)(b0 + b2) * NHID + e] = hnew;
        }
        if (tid >= 560) {  // pad cols 600..607 of both rows
            const int i = tid - 560, b2 = i / 8, c = i % 8;
            outb[(size_t)(t * BATCH + b0 + b2) * OUT_KP + NHID + c] = (bf16_t)0.f;
        }
        __syncthreads();   // B5: hsh stable before next step
    }
}

// ---------------- dec = outb @ decWT^T + dec_b (bf16 MFMA 16x16x32) ----------------

__global__ __launch_bounds__(256) void dec_gemm(const bf16_t* __restrict__ Ag,
                                                const bf16_t* __restrict__ Bg,
                                                const float* __restrict__ bias,
                                                float* __restrict__ C) {
    __shared__ bf16_t As[128][32];
    __shared__ bf16_t Bs[64][32];
    const int tid = threadIdx.x;
    const int wave = tid >> 6, lane = tid & 63;
    const int m0 = blockIdx.x * 128, n0 = blockIdx.y * 64;
    f32x4 acc[2][4] = {};
    for (int k0 = 0; k0 < OUT_KP; k0 += 32) {
#pragma unroll
        for (int ii = 0; ii < 2; ii++) {
            int el = (tid + ii * 256) * 8;
            int row = el >> 5, col = el & 31;
            *(float4*)&As[row][col] = *(const float4*)(Ag + (size_t)(m0 + row) * OUT_KP + k0 + col);
        }
        {
            int el = tid * 8;
            int row = el >> 5, col = el & 31;
            *(float4*)&Bs[row][col] = *(const float4*)(Bg + (size_t)(n0 + row) * OUT_KP + k0 + col);
        }
        __syncthreads();
        const int fm = lane & 15, fq = (lane >> 4) * 8;
        bf16x8 a[2], bb[4];
        a[0] = *(const bf16x8*)&As[wave * 32 + fm][fq];
        a[1] = *(const bf16x8*)&As[wave * 32 + 16 + fm][fq];
#pragma unroll
        for (int nt = 0; nt < 4; nt++) bb[nt] = *(const bf16x8*)&Bs[nt * 16 + fm][fq];
#pragma unroll
        for (int mt = 0; mt < 2; mt++)
#pragma unroll
            for (int nt = 0; nt < 4; nt++)
                acc[mt][nt] = __builtin_amdgcn_mfma_f32_16x16x32_bf16(a[mt], bb[nt], acc[mt][nt], 0, 0, 0);
        __syncthreads();
    }
    const int fm = lane & 15, fr = (lane >> 4) * 4;
#pragma unroll
    for (int mt = 0; mt < 2; mt++)
#pragma unroll
        for (int nt = 0; nt < 4; nt++) {
            int n = n0 + nt * 16 + fm;
            float bia = bias[n];
#pragma unroll
            for (int r = 0; r < 4; r++) {
                int m = m0 + wave * 32 + mt * 16 + fr + r;
                C[(size_t)m * NTOKC + n] = acc[mt][nt][r] + bia;
            }
        }
}

// ---------------- launch ----------------

extern "C" void kernel_launch(void* const* d_in, const int* in_sizes, int n_in,
                              void* d_out, int out_size, void* d_ws, size_t ws_size,
                              hipStream_t stream) {
    const float* input  = (const float*)d_in[0];
    const float* hidden = (const float*)d_in[1];
    const float* masks  = (const float*)d_in[2];
    const float* encW   = (const float*)d_in[3];
    const float* encB   = (const float*)d_in[4];
    const float* Wq     = (const float*)d_in[5];
    const float* Wk     = (const float*)d_in[6];
    const float* Wv     = (const float*)d_in[7];
    const float* Wx     = (const float*)d_in[8];
    const float* Wh     = (const float*)d_in[9];
    const float* grub   = (const float*)d_in[10];
    const float* Wq2    = (const float*)d_in[11];
    const float* Wk2    = (const float*)d_in[12];
    const float* Wv2    = (const float*)d_in[13];
    const float* decW   = (const float*)d_in[14];
    const float* decB   = (const float*)d_in[15];

    char* ws = (char*)d_ws;
    float*  KU    = (float*)(ws + WS_KU);
    bf16_t* outb  = (bf16_t*)(ws + WS_OUTB);
    float*  W1    = (float*)(ws + WS_W1);
    float*  b1    = (float*)(ws + WS_B1);
    float*  WvWx  = (float*)(ws + WS_WVWX);
    bf16_t* decWT = (bf16_t*)(ws + WS_DECWT);

    float* out_dec = (float*)d_out;
    float* out_hT  = out_dec + 16777216;   // T*B*NTOK
    float* out_bm  = out_dec + 17084416;   // + B*NHID

    prep_wvwx<<<(NINP * 300 + 255) / 256, 256, 0, stream>>>(Wv, Wx, WvWx);
    prep_w1<<<(NTOKC * KU_N + 255) / 256, 256, 0, stream>>>(encW, Wk, WvWx, W1);
    prep_b1<<<2, 256, 0, stream>>>(encB, Wk, WvWx, b1);
    prep_decwt<<<(NTOKC * OUT_KP + 255) / 256, 256, 0, stream>>>(decW, decWT);
    ku_gemm<<<dim3(256, 6), 256, 0, stream>>>(input, W1, b1, KU);
    scan_kernel<<<256, 576, 0, stream>>>(hidden, masks, Wq, Wh, grub, Wq2, Wk2, Wv2,
                                         KU, outb, out_hT, out_bm);
    dec_gemm<<<dim3(256, 8), 256, 0, stream>>>(outb, decWT, decB, out_dec);
}